// Round 1
// baseline (152.742 us; speedup 1.0000x reference)
//
#include <hip/hip_runtime.h>
#include <hip/hip_bf16.h>

// NT-Xent loss, MI355X. Pipeline:
//  k_normalize : fp32 row-norms, zn = bf16(z/norm)                 [N,D]
//  k_pos       : exact fp32 positives pos[i]=dot(zn_i,zn_{i+B})/T  [N]
//  k_flash     : flash-LSE over sim = zn@zn^T via MFMA bf16, label mask,
//                per-(split,row) running (M,S) partials
//  k_finalize  : combine partials + pos -> sum(lse-pos)/N -> d_out[0]

#define B_ 4096
#define N_ 8192
#define D_ 256
#define INV_T 2.0f      // 1/TEMPERATURE
#define EPS_ 1e-8f
#define NEGINF_ (-1e30f)
#define SPLITS 8
#define BM 128          // rows per block (4 waves x 32 rows)
#define BN 64           // cols per LDS tile
#define KC 8            // D_/32 k-chunks per MFMA K
#define CPS (N_ / SPLITS)   // 1024 cols per split
#define NT_ (CPS / BN)      // 16 tiles per split

typedef __attribute__((ext_vector_type(8))) short bfrag_t;   // 8 bf16 = 4 VGPR
typedef __attribute__((ext_vector_type(4))) float f32x4_t;   // MFMA C/D

__device__ inline ushort f2bf_rne(float x) {
  union { float f; unsigned u; } a; a.f = x;
  unsigned r = a.u + 0x7FFFu + ((a.u >> 16) & 1u);
  return (ushort)(r >> 16);
}

// ---------------- normalize: one wave per row ----------------
__global__ __launch_bounds__(256) void k_normalize(
    const float* __restrict__ zi, const float* __restrict__ zj,
    ushort* __restrict__ zn, float* __restrict__ norms) {
  const int w = threadIdx.x >> 6, lane = threadIdx.x & 63;
  const int row = blockIdx.x * 4 + w;
  const float* src = (row < B_) ? (zi + (size_t)row * D_)
                                : (zj + (size_t)(row - B_) * D_);
  float4 v = reinterpret_cast<const float4*>(src)[lane];
  float ss = v.x * v.x + v.y * v.y + v.z * v.z + v.w * v.w;
#pragma unroll
  for (int d = 1; d < 64; d <<= 1) ss += __shfl_xor(ss, d);
  float nrm = fmaxf(sqrtf(ss), EPS_);
  float inv = 1.0f / nrm;
  ushort4 o;
  o.x = f2bf_rne(v.x * inv); o.y = f2bf_rne(v.y * inv);
  o.z = f2bf_rne(v.z * inv); o.w = f2bf_rne(v.w * inv);
  reinterpret_cast<ushort4*>(zn + (size_t)row * D_)[lane] = o;
  if (lane == 0) norms[row] = nrm;
}

// ---------------- positives: one wave per pair (exact fp32) ----------------
__global__ __launch_bounds__(256) void k_pos(
    const float* __restrict__ zi, const float* __restrict__ zj,
    const float* __restrict__ norms, float* __restrict__ pos) {
  const int w = threadIdx.x >> 6, lane = threadIdx.x & 63;
  const int p = blockIdx.x * 4 + w;  // p in [0,B)
  float4 a = reinterpret_cast<const float4*>(zi + (size_t)p * D_)[lane];
  float4 b = reinterpret_cast<const float4*>(zj + (size_t)p * D_)[lane];
  float d = a.x * b.x + a.y * b.y + a.z * b.z + a.w * b.w;
#pragma unroll
  for (int dd = 1; dd < 64; dd <<= 1) d += __shfl_xor(d, dd);
  if (lane == 0) {
    float v = d / (norms[p] * norms[p + B_]) * INV_T;
    pos[p] = v;
    pos[p + B_] = v;
  }
}

// ---------------- flash LSE over sim tiles ----------------
__global__ __launch_bounds__(256) void k_flash(
    const ushort* __restrict__ zn, const int* __restrict__ labels,
    float* __restrict__ Mpart, float* __restrict__ Spart) {
  __shared__ uint4 lds16[BN * (D_ / 8)];  // 64 rows x 32 x 16B = 32 KB
  const int tid = threadIdx.x;
  const int w = tid >> 6, lane = tid & 63;
  const int l15 = lane & 15, l4 = lane >> 4;
  const int arowb = blockIdx.x * BM + w * 32;
  const int split = blockIdx.y;

  // A fragments: 32 rows x 256 K held in registers for the whole block.
  // lane l supplies row (l&15), k = kc*32 + (l>>4)*8 .. +7 (16B contiguous).
  bfrag_t a[2][KC];
#pragma unroll
  for (int mf = 0; mf < 2; ++mf) {
    const int ar = arowb + mf * 16 + l15;
#pragma unroll
    for (int kc = 0; kc < KC; ++kc)
      a[mf][kc] = *reinterpret_cast<const bfrag_t*>(
          zn + (size_t)ar * D_ + kc * 32 + l4 * 8);
  }

  int labR[2][4];
#pragma unroll
  for (int mf = 0; mf < 2; ++mf)
#pragma unroll
    for (int rg = 0; rg < 4; ++rg)
      labR[mf][rg] = labels[(arowb + mf * 16 + l4 * 4 + rg) & (B_ - 1)];

  float Mrun[2][4], Srun[2][4];
#pragma unroll
  for (int mf = 0; mf < 2; ++mf)
#pragma unroll
    for (int rg = 0; rg < 4; ++rg) { Mrun[mf][rg] = NEGINF_; Srun[mf][rg] = 0.f; }

  const uint4* g16base = reinterpret_cast<const uint4*>(zn);

  for (int ct = 0; ct < NT_; ++ct) {
    const int cb = split * CPS + ct * BN;
    __syncthreads();
    // stage 64 cols x 256 k, XOR-swizzled in 16B units: c' = c ^ (row&7)
    const uint4* g16 = g16base + (size_t)cb * (D_ / 8);
#pragma unroll
    for (int p = 0; p < (BN * (D_ / 8)) / 256; ++p) {
      int u = p * 256 + tid;
      int rw = u >> 5, c = u & 31;
      lds16[rw * 32 + (c ^ (rw & 7))] = g16[u];
    }
    __syncthreads();

    int labC[4];
#pragma unroll
    for (int nf = 0; nf < 4; ++nf)
      labC[nf] = labels[(cb + nf * 16 + l15) & (B_ - 1)];

    f32x4_t acc[2][4];
#pragma unroll
    for (int mf = 0; mf < 2; ++mf)
#pragma unroll
      for (int nf = 0; nf < 4; ++nf)
        acc[mf][nf] = (f32x4_t){0.f, 0.f, 0.f, 0.f};

#pragma unroll
    for (int kc = 0; kc < KC; ++kc) {
#pragma unroll
      for (int nf = 0; nf < 4; ++nf) {
        const int br = nf * 16 + l15;
        const int cu = kc * 4 + l4;
        bfrag_t bf = *reinterpret_cast<const bfrag_t*>(
            &lds16[br * 32 + (cu ^ (br & 7))]);
        acc[0][nf] = __builtin_amdgcn_mfma_f32_16x16x32_bf16(a[0][kc], bf, acc[0][nf], 0, 0, 0);
        acc[1][nf] = __builtin_amdgcn_mfma_f32_16x16x32_bf16(a[1][kc], bf, acc[1][nf], 0, 0, 0);
      }
    }

    // online LSE update. C/D layout: col = lane&15 (within nf tile),
    // row = (lane>>4)*4 + rg. Row state lives per (mf,rg) per l4-group;
    // shfl_xor over lane bits 0..3 reduces across the 16 cols of one row.
#pragma unroll
    for (int mf = 0; mf < 2; ++mf) {
#pragma unroll
      for (int rg = 0; rg < 4; ++rg) {
        const int rl = labR[mf][rg];
        float v[4]; bool ok[4];
#pragma unroll
        for (int nf = 0; nf < 4; ++nf) {
          v[nf] = acc[mf][nf][rg] * INV_T;
          ok[nf] = (labC[nf] != rl);
        }
        float mx = NEGINF_;
#pragma unroll
        for (int nf = 0; nf < 4; ++nf) mx = fmaxf(mx, ok[nf] ? v[nf] : NEGINF_);
#pragma unroll
        for (int d = 1; d < 16; d <<= 1) mx = fmaxf(mx, __shfl_xor(mx, d));
        const float Mo = Mrun[mf][rg];
        const float Mn = fmaxf(Mo, mx);
        const float sc = __expf(Mo - Mn);  // Mo=Mn=NEGINF -> 1, but S=0
        float add = 0.f;
#pragma unroll
        for (int nf = 0; nf < 4; ++nf)
          add += ok[nf] ? __expf(v[nf] - Mn) : 0.f;
        Srun[mf][rg] = Srun[mf][rg] * sc + add;
        Mrun[mf][rg] = Mn;
      }
    }
  }

  // write per-(split,row) partials; S needs the cross-lane (col) sum
#pragma unroll
  for (int mf = 0; mf < 2; ++mf) {
#pragma unroll
    for (int rg = 0; rg < 4; ++rg) {
      float s = Srun[mf][rg];
#pragma unroll
      for (int d = 1; d < 16; d <<= 1) s += __shfl_xor(s, d);
      if (l15 == 0) {
        const int row = arowb + mf * 16 + l4 * 4 + rg;
        Mpart[(size_t)split * N_ + row] = Mrun[mf][rg];
        Spart[(size_t)split * N_ + row] = s;
      }
    }
  }
}

// ---------------- finalize: combine splits + pos, reduce to scalar ----------------
__global__ __launch_bounds__(256) void k_finalize(
    const float* __restrict__ Mpart, const float* __restrict__ Spart,
    const float* __restrict__ pos, float* __restrict__ out) {
  __shared__ float red[4];
  const int i = blockIdx.x * 256 + threadIdx.x;
  const float p = pos[i];
  float Mt = p;
#pragma unroll
  for (int s = 0; s < SPLITS; ++s) Mt = fmaxf(Mt, Mpart[s * N_ + i]);
  float sum = __expf(p - Mt);
#pragma unroll
  for (int s = 0; s < SPLITS; ++s)
    sum += Spart[s * N_ + i] * __expf(Mpart[s * N_ + i] - Mt);
  float c = Mt + __logf(sum) - p;  // lse_i - pos_i
#pragma unroll
  for (int d = 1; d < 64; d <<= 1) c += __shfl_xor(c, d);
  const int w = threadIdx.x >> 6, lane = threadIdx.x & 63;
  if (lane == 0) red[w] = c;
  __syncthreads();
  if (threadIdx.x == 0) {
    float t = red[0] + red[1] + red[2] + red[3];
    atomicAdd(out, t * (1.0f / (float)N_));
  }
}

extern "C" void kernel_launch(void* const* d_in, const int* in_sizes, int n_in,
                              void* d_out, int out_size, void* d_ws, size_t ws_size,
                              hipStream_t stream) {
  (void)in_sizes; (void)n_in; (void)out_size; (void)ws_size;
  const float* zi = (const float*)d_in[0];
  const float* zj = (const float*)d_in[1];
  const int* labels = (const int*)d_in[2];
  char* ws = (char*)d_ws;
  ushort* zn   = (ushort*)(ws);                                  // 4 MB
  float* norms = (float*)(ws + 4u * 1024 * 1024);                // 32 KB
  float* pos   = (float*)(ws + 4u * 1024 * 1024 + 32 * 1024);    // 32 KB
  float* Mpart = (float*)(ws + 4u * 1024 * 1024 + 64 * 1024);    // 256 KB
  float* Spart = (float*)(ws + 4u * 1024 * 1024 + 320 * 1024);   // 256 KB
  float* out = (float*)d_out;

  hipMemsetAsync(out, 0, sizeof(float), stream);
  k_normalize<<<N_ / 4, 256, 0, stream>>>(zi, zj, zn, norms);
  k_pos<<<B_ / 4, 256, 0, stream>>>(zi, zj, norms, pos);
  k_flash<<<dim3(N_ / BM, SPLITS), 256, 0, stream>>>(zn, labels, Mpart, Spart);
  k_finalize<<<N_ / 256, 256, 0, stream>>>(Mpart, Spart, pos, out);
}

// Round 2
// 108.644 us; speedup vs baseline: 1.4059x; 1.4059x over previous
//
#include <hip/hip_runtime.h>
#include <hip/hip_bf16.h>

// NT-Xent loss, MI355X, round 2.
//  k_prep     : fused fp32 row-norms + bf16 normalize + exact positives
//  k_flash    : sim = zn@zn^T via MFMA bf16, FIXED-max LSE (logits<=2),
//               async global_load_lds staging hidden under exp epilogue
//  k_finalize : sum splits + pos -> sum(lse-pos)/N -> d_out[0]

#define B_ 4096
#define N_ 8192
#define D_ 256
#define EPS_ 1e-8f
#define SPLITS 16
#define BM 128              // rows per block (4 waves x 32 rows)
#define BN 64               // cols per LDS tile
#define KC 8                // D/32 k-chunks
#define CPS (N_ / SPLITS)   // 512 cols per split
#define NT_ (CPS / BN)      // 8 tiles per split
#define LOG2E 1.44269504088896340736f

typedef __attribute__((ext_vector_type(8))) short bfrag_t;   // 8 bf16
typedef __attribute__((ext_vector_type(4))) float f32x4_t;   // MFMA C/D

__device__ __forceinline__ ushort f2bf_rne(float x) {
  union { float f; unsigned u; } a; a.f = x;
  unsigned r = a.u + 0x7FFFu + ((a.u >> 16) & 1u);
  return (ushort)(r >> 16);
}

__device__ __forceinline__ void cp16_lds(const uint4* g, uint4* l) {
  __builtin_amdgcn_global_load_lds(
      (const __attribute__((address_space(1))) unsigned int*)g,
      (__attribute__((address_space(3))) unsigned int*)l, 16, 0, 0);
}

// ---------------- fused normalize + positives: one wave per pair ----------------
__global__ __launch_bounds__(256) void k_prep(
    const float* __restrict__ zi, const float* __restrict__ zj,
    ushort* __restrict__ zn, float* __restrict__ pos) {
  const int w = threadIdx.x >> 6, lane = threadIdx.x & 63;
  const int p = blockIdx.x * 4 + w;
  float4 a = reinterpret_cast<const float4*>(zi + (size_t)p * D_)[lane];
  float4 b = reinterpret_cast<const float4*>(zj + (size_t)p * D_)[lane];
  float si = a.x * a.x + a.y * a.y + a.z * a.z + a.w * a.w;
  float sj = b.x * b.x + b.y * b.y + b.z * b.z + b.w * b.w;
  float dd = a.x * b.x + a.y * b.y + a.z * b.z + a.w * b.w;
#pragma unroll
  for (int d = 1; d < 64; d <<= 1) {
    si += __shfl_xor(si, d);
    sj += __shfl_xor(sj, d);
    dd += __shfl_xor(dd, d);
  }
  const float ni = fmaxf(sqrtf(si), EPS_), nj = fmaxf(sqrtf(sj), EPS_);
  const float ii = 1.0f / ni, ij = 1.0f / nj;
  ushort4 oi, oj;
  oi.x = f2bf_rne(a.x * ii); oi.y = f2bf_rne(a.y * ii);
  oi.z = f2bf_rne(a.z * ii); oi.w = f2bf_rne(a.w * ii);
  oj.x = f2bf_rne(b.x * ij); oj.y = f2bf_rne(b.y * ij);
  oj.z = f2bf_rne(b.z * ij); oj.w = f2bf_rne(b.w * ij);
  reinterpret_cast<ushort4*>(zn + (size_t)p * D_)[lane] = oi;
  reinterpret_cast<ushort4*>(zn + (size_t)(p + B_) * D_)[lane] = oj;
  if (lane == 0) {
    float v = dd / (ni * nj) * 2.0f;   // /T with T=0.5
    pos[p] = v;
    pos[p + B_] = v;
  }
}

// ---------------- flash LSE (fixed max = 2) ----------------
__global__ __launch_bounds__(256) void k_flash(
    const ushort* __restrict__ zn, const int* __restrict__ labels,
    float* __restrict__ Spart) {
  __shared__ uint4 lds16[BN * 32];   // 64 cols x 256 k bf16 = 32 KB, swizzled
  const int tid = threadIdx.x;
  const int w = tid >> 6, lane = tid & 63;
  const int l15 = lane & 15, l4 = lane >> 4;
  const int c31 = lane & 31, lh = lane >> 5;
  const int arowb = blockIdx.x * BM + w * 32;
  const int split = blockIdx.y;

  // A fragments: 32 rows x 256 K in registers for the whole block.
  bfrag_t a[2][KC];
#pragma unroll
  for (int mf = 0; mf < 2; ++mf) {
    const int ar = arowb + mf * 16 + l15;
#pragma unroll
    for (int kc = 0; kc < KC; ++kc)
      a[mf][kc] = *reinterpret_cast<const bfrag_t*>(
          zn + (size_t)ar * D_ + kc * 32 + l4 * 8);
  }

  int labR[2][4];
#pragma unroll
  for (int mf = 0; mf < 2; ++mf)
#pragma unroll
    for (int rg = 0; rg < 4; ++rg)
      labR[mf][rg] = labels[(arowb + mf * 16 + l4 * 4 + rg) & (B_ - 1)];

  float Srun[2][4];
#pragma unroll
  for (int mf = 0; mf < 2; ++mf)
#pragma unroll
    for (int rg = 0; rg < 4; ++rg) Srun[mf][rg] = 0.f;

  const uint4* g16 = reinterpret_cast<const uint4*>(zn);

  // async stage of one 64-col tile: linear LDS dest, pre-swizzled global src.
  // LDS[rw*32 + c'] must hold G[(cb+rw)*32 + (c' ^ (rw&7))].
  auto stage = [&](int ct) {
    const int cb = split * CPS + ct * BN;
    const uint4* gt = g16 + (size_t)cb * 32;
#pragma unroll
    for (int q = 0; q < 8; ++q) {
      const int rw = w * 16 + q * 2 + lh;
      const int src = rw * 32 + (c31 ^ (rw & 7));
      cp16_lds(gt + src, lds16 + (w * 512 + q * 64));
    }
  };

  stage(0);

  for (int ct = 0; ct < NT_; ++ct) {
    const int cb = split * CPS + ct * BN;
    __syncthreads();   // drains vmcnt(0): tile ct is in LDS for all waves

    int labC[4];
#pragma unroll
    for (int nf = 0; nf < 4; ++nf)
      labC[nf] = labels[(cb + nf * 16 + l15) & (B_ - 1)];

    f32x4_t acc[2][4];
#pragma unroll
    for (int mf = 0; mf < 2; ++mf)
#pragma unroll
      for (int nf = 0; nf < 4; ++nf)
        acc[mf][nf] = (f32x4_t){0.f, 0.f, 0.f, 0.f};

#pragma unroll
    for (int kc = 0; kc < KC; ++kc) {
#pragma unroll
      for (int nf = 0; nf < 4; ++nf) {
        const int br = nf * 16 + l15;
        const int cu = kc * 4 + l4;
        bfrag_t bf = *reinterpret_cast<const bfrag_t*>(
            &lds16[br * 32 + (cu ^ (br & 7))]);
        acc[0][nf] = __builtin_amdgcn_mfma_f32_16x16x32_bf16(a[0][kc], bf, acc[0][nf], 0, 0, 0);
        acc[1][nf] = __builtin_amdgcn_mfma_f32_16x16x32_bf16(a[1][kc], bf, acc[1][nf], 0, 0, 0);
      }
    }

    __syncthreads();                  // all waves done reading tile ct
    if (ct + 1 < NT_) stage(ct + 1);  // async refill flies under the epilogue

    // fixed-max epilogue: S += exp(sim*2 - 2), masked by label equality.
    // exp(v-2) = exp2(acc*2*log2e - 2*log2e); args in [-5.8, 0].
#pragma unroll
    for (int mf = 0; mf < 2; ++mf) {
#pragma unroll
      for (int rg = 0; rg < 4; ++rg) {
        const int rl = labR[mf][rg];
        float s0 = 0.f, s1 = 0.f;
#pragma unroll
        for (int nf = 0; nf < 4; ++nf) {
          float t = fmaf(acc[mf][nf][rg], 2.0f * LOG2E, -2.0f * LOG2E);
          float e = __builtin_amdgcn_exp2f(t);
          e = (labC[nf] != rl) ? e : 0.0f;
          if (nf & 1) s1 += e; else s0 += e;
        }
        Srun[mf][rg] += s0 + s1;
      }
    }
  }

  // cross-lane (16 cols) sum, one write per row per split
#pragma unroll
  for (int mf = 0; mf < 2; ++mf) {
#pragma unroll
    for (int rg = 0; rg < 4; ++rg) {
      float s = Srun[mf][rg];
#pragma unroll
      for (int d = 1; d < 16; d <<= 1) s += __shfl_xor(s, d);
      if (l15 == 0)
        Spart[(size_t)split * N_ + arowb + mf * 16 + l4 * 4 + rg] = s;
    }
  }
}

// ---------------- finalize ----------------
__global__ __launch_bounds__(256) void k_finalize(
    const float* __restrict__ Spart, const float* __restrict__ pos,
    float* __restrict__ out) {
  __shared__ float red[4];
  const int i = blockIdx.x * 256 + threadIdx.x;
  const float p = pos[i];
  float S = __builtin_amdgcn_exp2f(fmaf(p, LOG2E, -2.0f * LOG2E));  // exp(p-2)
#pragma unroll
  for (int s = 0; s < SPLITS; ++s) S += Spart[s * N_ + i];
  float c = 2.0f + __logf(S) - p;   // lse_i - pos_i
#pragma unroll
  for (int d = 1; d < 64; d <<= 1) c += __shfl_xor(c, d);
  const int w = threadIdx.x >> 6, lane = threadIdx.x & 63;
  if (lane == 0) red[w] = c;
  __syncthreads();
  if (threadIdx.x == 0) {
    float t = red[0] + red[1] + red[2] + red[3];
    atomicAdd(out, t * (1.0f / (float)N_));
  }
}

extern "C" void kernel_launch(void* const* d_in, const int* in_sizes, int n_in,
                              void* d_out, int out_size, void* d_ws, size_t ws_size,
                              hipStream_t stream) {
  (void)in_sizes; (void)n_in; (void)out_size; (void)ws_size;
  const float* zi = (const float*)d_in[0];
  const float* zj = (const float*)d_in[1];
  const int* labels = (const int*)d_in[2];
  char* ws = (char*)d_ws;
  ushort* zn   = (ushort*)(ws);                               // 4 MB
  float* pos   = (float*)(ws + 4u * 1024 * 1024);             // 32 KB
  float* Spart = (float*)(ws + 4u * 1024 * 1024 + 32 * 1024); // 512 KB
  float* out = (float*)d_out;

  hipMemsetAsync(out, 0, sizeof(float), stream);
  k_prep<<<B_ / 4, 256, 0, stream>>>(zi, zj, zn, pos);
  k_flash<<<dim3(N_ / BM, SPLITS), 256, 0, stream>>>(zn, labels, Spart);
  k_finalize<<<N_ / 256, 256, 0, stream>>>(Spart, pos, out);
}